// Round 7
// baseline (290.681 us; speedup 1.0000x reference)
//
#include <hip/hip_runtime.h>
#include <hip/hip_fp16.h>

// Problem sizes (fixed): b=2, c=64, 48x48 -> n=2304, heads=4, hd=16, 3c=192
// n = 2304 = 9*256 exactly; 2304 = 144*16 col-tiles.
//
// QK^T strategy: q,k stored as f16 split pairs interleaved [v(16)|res(16)]
// per row (32 halves = 64 B). One 16x16x32_f16 MFMA with A=[q1|qr],
// B=[k1|k1] gives q1k1+qrk1; a second with A=[q1|0], B=[kr|*] adds q1kr.
// Sum = (q1+qr)(k1+kr) - qr*kr  ->  fp32-accurate logits, no fp32 q/k kept.

#define NEG_INF (-__builtin_huge_valf())

typedef _Float16 half8_t __attribute__((ext_vector_type(8)));
typedef float floatx4 __attribute__((ext_vector_type(4)));

// 16-bit monotone key map for half-precision values.
__device__ __forceinline__ unsigned h2key(unsigned short u) {
  return (u & 0x8000u) ? (unsigned)((~u) & 0xFFFFu) : (unsigned)(u | 0x8000u);
}
__device__ __forceinline__ float key16_to_float(unsigned k) {
  unsigned short u = (k & 0x8000u) ? (unsigned short)(k & 0x7FFFu)
                                   : (unsigned short)((~k) & 0xFFFFu);
  return __half2float(__ushort_as_half(u));
}

// K1: 1x1 conv qkv = Wqkv @ x + bqkv.  out[b,o,pos], grid = 2*192*9 blocks.
__global__ __launch_bounds__(256) void k_qkv(const float* __restrict__ x,
                                             const float* __restrict__ W,
                                             const float* __restrict__ bias,
                                             float* __restrict__ out) {
  int blk = blockIdx.x;
  int chunk = blk % 9;
  int o = (blk / 9) % 192;
  int b = blk / (9 * 192);
  int pos = chunk * 256 + threadIdx.x;
  const float* xb = x + b * 64 * 2304 + pos;
  const float* wr = W + o * 64;
  float acc = bias[o];
#pragma unroll
  for (int c = 0; c < 64; c++) acc = fmaf(wr[c], xb[c * 2304], acc);
  out[(b * 192 + o) * 2304 + pos] = acc;
}

// K2: 3x3 depthwise conv (SAME) + bias; q/k written as f16 split pairs in
// MFMA fragment layout [row][v(16)|res(16)]; v stays fp32 head layout.
// q gets *0.25 (softmax scale folded in).
__global__ __launch_bounds__(256) void k_dw(const float* __restrict__ qkv,
                                            const float* __restrict__ Wpos,
                                            const float* __restrict__ bpos,
                                            _Float16* __restrict__ q2,
                                            _Float16* __restrict__ k2,
                                            float* __restrict__ vh) {
  int blk = blockIdx.x;
  int chunk = blk % 9;
  int ch = (blk / 9) % 192;
  int b = blk / (9 * 192);
  int pos = chunk * 256 + threadIdx.x;
  int yy = pos / 48, xx = pos % 48;
  const float* in = qkv + (b * 192 + ch) * 2304;
  const float* w = Wpos + ch * 9;
  float acc = bpos[ch];
#pragma unroll
  for (int dy = -1; dy <= 1; dy++) {
    int y2 = yy + dy;
    if ((unsigned)y2 < 48u) {
#pragma unroll
      for (int dx = -1; dx <= 1; dx++) {
        int x2 = xx + dx;
        if ((unsigned)x2 < 48u)
          acc = fmaf(w[(dy + 1) * 3 + (dx + 1)], in[y2 * 48 + x2], acc);
      }
    }
  }
  int sel = ch >> 6;
  int c = ch & 63;
  int head = c >> 4, d = c & 15;
  size_t idx = (size_t)(b * 4 + head) * 2304 + pos;
  if (sel == 2) {
    vh[idx * 16 + d] = acc;
  } else {
    if (sel == 0) acc *= 0.25f;  // scale = hd^-0.5 = 0.25 folded into q
    _Float16 h1 = (_Float16)acc;
    float r = acc - (float)h1;
    _Float16 h2 = (_Float16)r;
    _Float16* dst = (sel == 0) ? q2 : k2;
    dst[idx * 32 + d] = h1;
    dst[idx * 32 + 16 + d] = h2;
  }
}

// K3: entropy of full softmax per row via MFMA QK^T (no logit store).
// grid = 8 bh * 144 rowtiles (16 rows each); wave w covers cols [w*576,..).
// Two passes over 36 col-tiles: (1) row max, (2) exp-sums S, U.
__global__ __launch_bounds__(256) void k_ent(const _Float16* __restrict__ q2,
                                             const _Float16* __restrict__ k2,
                                             float* __restrict__ ent) {
  int blk = blockIdx.x;
  int rowtile = blk % 144;
  int bh = blk / 144;
  int row0 = rowtile * 16;
  int tid = threadIdx.x, lane = tid & 63, wave = tid >> 6;
  int m16 = lane & 15, quad = lane >> 4;

  const half8_t* q2v =
      (const half8_t*)(q2 + ((size_t)bh * 2304 + row0 + m16) * 32);
  half8_t A1 = q2v[quad];  // [q1|qr] fragment: quad*8 halves
  half8_t zh = {};
  half8_t A2 = (lane < 32) ? A1 : zh;  // [q1|0]
  const half8_t* kbase = (const half8_t*)(k2 + (size_t)bh * 2304 * 32);

  // ---- pass 1: row max ----
  float mreg[4] = {NEG_INF, NEG_INF, NEG_INF, NEG_INF};
#pragma unroll 4
  for (int t = 0; t < 36; t++) {
    int col = wave * 576 + t * 16 + m16;
    const half8_t* kk = kbase + (size_t)col * 4;
    half8_t b1 = kk[quad & 1];        // k1 halves
    half8_t b2 = kk[2 + (quad & 1)];  // kr halves
    floatx4 acc = {};
    acc = __builtin_amdgcn_mfma_f32_16x16x32_f16(A2, b2, acc, 0, 0, 0);
    acc = __builtin_amdgcn_mfma_f32_16x16x32_f16(A1, b1, acc, 0, 0, 0);
#pragma unroll
    for (int i = 0; i < 4; i++) mreg[i] = fmaxf(mreg[i], acc[i]);
  }
#pragma unroll
  for (int off = 1; off < 16; off <<= 1)
#pragma unroll
    for (int i = 0; i < 4; i++)
      mreg[i] = fmaxf(mreg[i], __shfl_xor(mreg[i], off));

  __shared__ float mWv[4][16], sWv[4][16], uWv[4][16];
  if (m16 == 0) {
#pragma unroll
    for (int i = 0; i < 4; i++) mWv[wave][quad * 4 + i] = mreg[i];
  }
  __syncthreads();
  float mrow[4];
#pragma unroll
  for (int i = 0; i < 4; i++) {
    int r = quad * 4 + i;
    mrow[i] = fmaxf(fmaxf(mWv[0][r], mWv[1][r]), fmaxf(mWv[2][r], mWv[3][r]));
  }

  // ---- pass 2: S = sum e^z, U = sum z e^z (z = a - m) ----
  float s[4] = {0.f, 0.f, 0.f, 0.f}, u[4] = {0.f, 0.f, 0.f, 0.f};
#pragma unroll 4
  for (int t = 0; t < 36; t++) {
    int col = wave * 576 + t * 16 + m16;
    const half8_t* kk = kbase + (size_t)col * 4;
    half8_t b1 = kk[quad & 1];
    half8_t b2 = kk[2 + (quad & 1)];
    floatx4 acc = {};
    acc = __builtin_amdgcn_mfma_f32_16x16x32_f16(A2, b2, acc, 0, 0, 0);
    acc = __builtin_amdgcn_mfma_f32_16x16x32_f16(A1, b1, acc, 0, 0, 0);
#pragma unroll
    for (int i = 0; i < 4; i++) {
      float z = acc[i] - mrow[i];
      float e = __expf(z);
      s[i] += e;
      u[i] = fmaf(z, e, u[i]);
    }
  }
#pragma unroll
  for (int off = 1; off < 16; off <<= 1) {
#pragma unroll
    for (int i = 0; i < 4; i++) {
      s[i] += __shfl_xor(s[i], off);
      u[i] += __shfl_xor(u[i], off);
    }
  }
  if (m16 == 0) {
#pragma unroll
    for (int i = 0; i < 4; i++) {
      sWv[wave][quad * 4 + i] = s[i];
      uWv[wave][quad * 4 + i] = u[i];
    }
  }
  __syncthreads();
  if (tid < 16) {
    float S = sWv[0][tid] + sWv[1][tid] + sWv[2][tid] + sWv[3][tid];
    float U = uWv[0][tid] + uWv[1][tid] + uWv[2][tid] + uWv[3][tid];
    float er = __logf(S) - U / S;
    er += __shfl_xor(er, 1);
    er += __shfl_xor(er, 2);
    er += __shfl_xor(er, 4);
    er += __shfl_xor(er, 8);
    if (tid == 0) atomicAdd(&ent[bh], er);
  }
}

// K5: gate MLP + MFMA QK^T (4 valid rows/block) -> f16 LDS + per-row exact
// k-th (16-bit ballot search) + masked softmax + PV.
__global__ __launch_bounds__(256, 7) void k_attn(const _Float16* __restrict__ q2,
                                                 const _Float16* __restrict__ k2,
                                                 const float* __restrict__ vh,
                                                 const float* __restrict__ ent,
                                                 const float* __restrict__ Wg1,
                                                 const float* __restrict__ bg1,
                                                 const float* __restrict__ Wg2,
                                                 const float* __restrict__ bg2,
                                                 float* __restrict__ oh) {
  // 2304 j * 4 rows * 2B = 18432 B; also reused as fp32 reduce buf (16640 B).
  __shared__ __align__(16) unsigned long long ldsRaw[18432 / 8];
  __shared__ float mSh[4][4];
  __shared__ float thSh[4];
  __shared__ float sShW[4][4];

  uint2* lgt64 = (uint2*)ldsRaw;                              // [j] -> 4 halfs
  const unsigned short* lgtU = (const unsigned short*)ldsRaw; // [j*4+r]

  int blk = blockIdx.x;
  int rowblk = blk % 576;
  int bh = blk / 576;
  int row0 = rowblk * 4;
  int tid = threadIdx.x, lane = tid & 63, wave = tid >> 6;
  int m16 = lane & 15, quad = lane >> 4;

  const float4* vb = (const float4*)(vh + (size_t)bh * 2304 * 16);

  // ---- gate MLP: keep count (uniform across block) ----
  float eAvg = ent[bh] * (1.f / 2304.f);
  float gacc = bg2[0];
#pragma unroll
  for (int i = 0; i < 16; i++) {
    float h = fmaxf(fmaf(eAvg, Wg1[i], bg1[i]), 0.f);
    gacc = fmaf(h, Wg2[i], gacc);
  }
  float ratio = 0.9f / (1.f + __expf(-gacc)) + 0.1f;
  int kp = (int)ceilf(ratio * 2304.f);
  unsigned keep = (unsigned)min(max(kp, 1), 2304);

  // ---- phase A: MFMA logits -> LDS (f16, [j][r]); row max from fp32 ----
  // A rows: m16 clamped to 0..3 (rows 4..15 duplicate rows 0..3; their D
  // rows land in quads 1-3 and are never read).
  const half8_t* q2v =
      (const half8_t*)(q2 + ((size_t)bh * 2304 + row0 + (m16 & 3)) * 32);
  half8_t A1 = q2v[quad];
  half8_t zh = {};
  half8_t A2 = (lane < 32) ? A1 : zh;
  const half8_t* kbase = (const half8_t*)(k2 + (size_t)bh * 2304 * 32);

  float mreg[4] = {NEG_INF, NEG_INF, NEG_INF, NEG_INF};
#pragma unroll 4
  for (int t = 0; t < 36; t++) {
    int ct = wave * 36 + t;
    int col = ct * 16 + m16;
    const half8_t* kk = kbase + (size_t)col * 4;
    half8_t b1 = kk[quad & 1];
    half8_t b2 = kk[2 + (quad & 1)];
    floatx4 acc = {};
    acc = __builtin_amdgcn_mfma_f32_16x16x32_f16(A2, b2, acc, 0, 0, 0);
    acc = __builtin_amdgcn_mfma_f32_16x16x32_f16(A1, b1, acc, 0, 0, 0);
    if (lane < 16) {  // quad 0 holds rows 0-3 (regs) x col=lane
      int j = ct * 16 + lane;
      __half2 h01 = __floats2half2_rn(acc[0], acc[1]);
      __half2 h23 = __floats2half2_rn(acc[2], acc[3]);
      uint2 packed;
      packed.x = *(unsigned*)&h01;
      packed.y = *(unsigned*)&h23;
      lgt64[j] = packed;
#pragma unroll
      for (int i = 0; i < 4; i++) mreg[i] = fmaxf(mreg[i], acc[i]);
    }
  }
#pragma unroll
  for (int off = 1; off < 16; off <<= 1)
#pragma unroll
    for (int r = 0; r < 4; r++)
      mreg[r] = fmaxf(mreg[r], __shfl_xor(mreg[r], off));
  if (lane == 0) {
#pragma unroll
    for (int r = 0; r < 4; r++) mSh[wave][r] = mreg[r];
  }
  __syncthreads();
  float m[4];
#pragma unroll
  for (int r = 0; r < 4; r++)
    m[r] = fmaxf(fmaxf(mSh[0][r], mSh[1][r]), fmaxf(mSh[2][r], mSh[3][r]));

  // ---- phase B: row-per-wave exact k-th largest on 16-bit keys ----
  {
    int r = wave;  // each wave owns one row
    unsigned keys[36];
#pragma unroll
    for (int i = 0; i < 36; i++) {
      int j = lane + i * 64;
      keys[i] = h2key(lgtU[j * 4 + r]);
    }
    unsigned T = 0u;
    for (int bit = 15; bit >= 0; --bit) {
      unsigned cand = T | (1u << bit);
      unsigned cnt = 0u;
#pragma unroll
      for (int i = 0; i < 36; i++)
        cnt += (unsigned)__popcll(__ballot(keys[i] >= cand));
      if (cnt >= keep) {
        T = cand;  // uniform
        if (cnt == keep) break;
      }
    }
    if (lane == 0) thSh[r] = key16_to_float(T);
  }
  __syncthreads();  // all phase-B LDS reads done; th visible
  float th[4];
#pragma unroll
  for (int r = 0; r < 4; r++) th[r] = thSh[r];

  // ---- phase C1: p = masked exp, in-place (f16); sp partials ----
  float sp[4] = {0.f, 0.f, 0.f, 0.f};
#pragma unroll
  for (int jj = 0; jj < 9; jj++) {
    int j = tid + jj * 256;
    uint2 raw = lgt64[j];
    __half2 h01 = *(__half2*)&raw.x;
    __half2 h23 = *(__half2*)&raw.y;
    float2 a01 = __half22float2(h01);
    float2 a23 = __half22float2(h23);
    float av[4] = {a01.x, a01.y, a23.x, a23.y};
    float p[4];
#pragma unroll
    for (int r = 0; r < 4; r++) {
      p[r] = (av[r] >= th[r]) ? __expf(av[r] - m[r]) : 0.f;
      sp[r] += p[r];
    }
    __half2 p01 = __floats2half2_rn(p[0], p[1]);
    __half2 p23 = __floats2half2_rn(p[2], p[3]);
    uint2 packed;
    packed.x = *(unsigned*)&p01;
    packed.y = *(unsigned*)&p23;
    lgt64[j] = packed;
  }
#pragma unroll
  for (int off = 1; off < 64; off <<= 1)
#pragma unroll
    for (int r = 0; r < 4; r++) sp[r] += __shfl_xor(sp[r], off);
  if (lane == 0) {
#pragma unroll
    for (int r = 0; r < 4; r++) sShW[wave][r] = sp[r];
  }
  __syncthreads();

  // ---- phase C2: dense PV from f16 probs, d-quad split ----
  int dg = tid & 3, jg = tid >> 2;
  float acc[4][4];
#pragma unroll
  for (int r = 0; r < 4; r++)
#pragma unroll
    for (int i = 0; i < 4; i++) acc[r][i] = 0.f;
  for (int jj = 0; jj < 36; jj++) {
    int j = jg + jj * 64;
    float4 v4 = vb[j * 4 + dg];
    uint2 raw = lgt64[j];
    float2 p01 = __half22float2(*(__half2*)&raw.x);
    float2 p23 = __half22float2(*(__half2*)&raw.y);
    float p[4] = {p01.x, p01.y, p23.x, p23.y};
#pragma unroll
    for (int r = 0; r < 4; r++) {
      acc[r][0] = fmaf(p[r], v4.x, acc[r][0]);
      acc[r][1] = fmaf(p[r], v4.y, acc[r][1]);
      acc[r][2] = fmaf(p[r], v4.z, acc[r][2]);
      acc[r][3] = fmaf(p[r], v4.w, acc[r][3]);
    }
  }

  // ---- phase D: reduce over 64 j-groups via padded LDS (fp32 view) ----
  __syncthreads();  // all prob reads done; reuse buffer
  float* part = (float*)ldsRaw;  // stride 65 floats per j-group (16640 B)
#pragma unroll
  for (int r = 0; r < 4; r++)
#pragma unroll
    for (int i = 0; i < 4; i++)
      part[jg * 65 + r * 16 + dg * 4 + i] = acc[r][i];
  __syncthreads();
  if (tid < 64) {
    float t2 = 0.f;
    for (int g = 0; g < 64; g++) t2 += part[g * 65 + tid];
    int r = tid >> 4, d = tid & 15;
    float S = sShW[0][r] + sShW[1][r] + sShW[2][r] + sShW[3][r];
    oh[((size_t)(bh * 2304 + row0 + r)) * 16 + d] = t2 / S;
  }
}

// K6: output projection out[b,co,pos] = Wproj @ heads + bproj
__global__ __launch_bounds__(256) void k_proj(const float* __restrict__ oh,
                                              const float* __restrict__ Wp,
                                              const float* __restrict__ bp,
                                              float* __restrict__ out) {
  int blk = blockIdx.x;
  int chunk = blk % 9;
  int co = (blk / 9) % 64;
  int b = blk / (9 * 64);
  int pos = chunk * 256 + threadIdx.x;
  const float* wr = Wp + co * 64;
  float acc = bp[co];
#pragma unroll
  for (int head = 0; head < 4; head++) {
    const float4* op = (const float4*)(oh + ((size_t)((b * 4 + head) * 2304 + pos)) * 16);
#pragma unroll
    for (int p = 0; p < 4; p++) {
      float4 o4 = op[p];
      acc = fmaf(wr[head * 16 + p * 4 + 0], o4.x, acc);
      acc = fmaf(wr[head * 16 + p * 4 + 1], o4.y, acc);
      acc = fmaf(wr[head * 16 + p * 4 + 2], o4.z, acc);
      acc = fmaf(wr[head * 16 + p * 4 + 3], o4.w, acc);
    }
  }
  out[(b * 64 + co) * 2304 + pos] = acc;
}

extern "C" void kernel_launch(void* const* d_in, const int* in_sizes, int n_in,
                              void* d_out, int out_size, void* d_ws,
                              size_t ws_size, hipStream_t stream) {
  const float* x    = (const float*)d_in[0];
  const float* Wqkv = (const float*)d_in[1];
  const float* bqkv = (const float*)d_in[2];
  const float* Wpos = (const float*)d_in[3];
  const float* bpos = (const float*)d_in[4];
  const float* Wg1  = (const float*)d_in[5];
  const float* bg1  = (const float*)d_in[6];
  const float* Wg2  = (const float*)d_in[7];
  const float* bg2  = (const float*)d_in[8];
  const float* Wpr  = (const float*)d_in[9];
  const float* bpr  = (const float*)d_in[10];
  float* out = (float*)d_out;

  float* ws = (float*)d_ws;
  float* qkv_raw = ws;                // 2*192*2304 = 884736 floats
  float* vh = qkv_raw + 884736;       // 294912 floats
  float* oh = vh + 294912;            // 294912 floats
  float* ent = oh + 294912;           // 8 floats
  _Float16* q2 = (_Float16*)(ent + 8);        // 8*2304*32 = 589824 halves
  _Float16* k2 = q2 + 589824;                 // 589824 halves

  (void)hipMemsetAsync(ent, 0, 8 * sizeof(float), stream);
  hipLaunchKernelGGL(k_qkv, dim3(2 * 192 * 9), dim3(256), 0, stream,
                     x, Wqkv, bqkv, qkv_raw);
  hipLaunchKernelGGL(k_dw, dim3(2 * 192 * 9), dim3(256), 0, stream,
                     qkv_raw, Wpos, bpos, q2, k2, vh);
  hipLaunchKernelGGL(k_ent, dim3(8 * 144), dim3(256), 0, stream,
                     q2, k2, ent);
  hipLaunchKernelGGL(k_attn, dim3(8 * 576), dim3(256), 0, stream,
                     q2, k2, vh, ent, Wg1, bg1, Wg2, bg2, oh);
  hipLaunchKernelGGL(k_proj, dim3(2 * 64 * 9), dim3(256), 0, stream,
                     oh, Wpr, bpr, out);
}

// Round 8
// 241.661 us; speedup vs baseline: 1.2028x; 1.2028x over previous
//
#include <hip/hip_runtime.h>
#include <hip/hip_fp16.h>

// Problem sizes (fixed): b=2, c=64, 48x48 -> n=2304, heads=4, hd=16, 3c=192
// n = 2304 = 9*256 exactly; 2304 = 144*16 col-tiles.
//
// QK^T: q,k stored as f16 split pairs [v(16)|res(16)] per row (64 B).
// mfma_f32_16x16x32_f16 with A=[q1|qr],B=[k1|k1] then A=[q1|0],B=[kr|*]
// accumulates q1k1+qrk1+q1kr ~= fp32-accurate logits. Verified r7.
// k_ent computes QK^T once (16-row tiles) and stores the f16 logit cache
// in k_attn's [rowblk][j][r4] layout; k_attn phase A is 9 uint2 loads.

#define NEG_INF (-__builtin_huge_valf())

typedef _Float16 half8_t __attribute__((ext_vector_type(8)));
typedef float floatx4 __attribute__((ext_vector_type(4)));

// 16-bit monotone key map for half-precision values.
__device__ __forceinline__ unsigned h2key(unsigned short u) {
  return (u & 0x8000u) ? (unsigned)((~u) & 0xFFFFu) : (unsigned)(u | 0x8000u);
}
__device__ __forceinline__ float key16_to_float(unsigned k) {
  unsigned short u = (k & 0x8000u) ? (unsigned short)(k & 0x7FFFu)
                                   : (unsigned short)((~k) & 0xFFFFu);
  return __half2float(__ushort_as_half(u));
}

// K1: 1x1 conv qkv = Wqkv @ x + bqkv.  out[b,o,pos], grid = 2*192*9 blocks.
__global__ __launch_bounds__(256) void k_qkv(const float* __restrict__ x,
                                             const float* __restrict__ W,
                                             const float* __restrict__ bias,
                                             float* __restrict__ out) {
  int blk = blockIdx.x;
  int chunk = blk % 9;
  int o = (blk / 9) % 192;
  int b = blk / (9 * 192);
  int pos = chunk * 256 + threadIdx.x;
  const float* xb = x + b * 64 * 2304 + pos;
  const float* wr = W + o * 64;
  float acc = bias[o];
#pragma unroll
  for (int c = 0; c < 64; c++) acc = fmaf(wr[c], xb[c * 2304], acc);
  out[(b * 192 + o) * 2304 + pos] = acc;
}

// K2: 3x3 depthwise conv (SAME) + bias; q/k written as f16 split pairs in
// MFMA fragment layout [row][v(16)|res(16)]; v stays fp32 head layout.
// q gets *0.25 (softmax scale folded in).
__global__ __launch_bounds__(256) void k_dw(const float* __restrict__ qkv,
                                            const float* __restrict__ Wpos,
                                            const float* __restrict__ bpos,
                                            _Float16* __restrict__ q2,
                                            _Float16* __restrict__ k2,
                                            float* __restrict__ vh) {
  int blk = blockIdx.x;
  int chunk = blk % 9;
  int ch = (blk / 9) % 192;
  int b = blk / (9 * 192);
  int pos = chunk * 256 + threadIdx.x;
  int yy = pos / 48, xx = pos % 48;
  const float* in = qkv + (b * 192 + ch) * 2304;
  const float* w = Wpos + ch * 9;
  float acc = bpos[ch];
#pragma unroll
  for (int dy = -1; dy <= 1; dy++) {
    int y2 = yy + dy;
    if ((unsigned)y2 < 48u) {
#pragma unroll
      for (int dx = -1; dx <= 1; dx++) {
        int x2 = xx + dx;
        if ((unsigned)x2 < 48u)
          acc = fmaf(w[(dy + 1) * 3 + (dx + 1)], in[y2 * 48 + x2], acc);
      }
    }
  }
  int sel = ch >> 6;
  int c = ch & 63;
  int head = c >> 4, d = c & 15;
  size_t idx = (size_t)(b * 4 + head) * 2304 + pos;
  if (sel == 2) {
    vh[idx * 16 + d] = acc;
  } else {
    if (sel == 0) acc *= 0.25f;  // scale = hd^-0.5 = 0.25 folded into q
    _Float16 h1 = (_Float16)acc;
    float r = acc - (float)h1;
    _Float16 h2 = (_Float16)r;
    _Float16* dst = (sel == 0) ? q2 : k2;
    dst[idx * 32 + d] = h1;
    dst[idx * 32 + 16 + d] = h2;
  }
}

// K3: MFMA QK^T once: entropy per (b,head) + (STORE) f16 logit cache in
// [rowblk][j][r4] layout. grid = 8 bh * 144 rowtiles (16 rows each);
// wave w covers cols [w*576, w*576+576). Lane layout: m16 = col, quad
// holds rows quad*4..quad*4+3 in acc[0..3] -> exactly one rowblk's uint2.
template <bool STORE>
__global__ __launch_bounds__(256) void k_ent_t(const _Float16* __restrict__ q2,
                                               const _Float16* __restrict__ k2,
                                               float* __restrict__ ent,
                                               uint2* __restrict__ lgG) {
  int blk = blockIdx.x;
  int rowtile = blk % 144;
  int bh = blk / 144;
  int row0 = rowtile * 16;
  int tid = threadIdx.x, lane = tid & 63, wave = tid >> 6;
  int m16 = lane & 15, quad = lane >> 4;

  const half8_t* q2v =
      (const half8_t*)(q2 + ((size_t)bh * 2304 + row0 + m16) * 32);
  half8_t A1 = q2v[quad];  // [q1|qr] fragment: quad*8 halves
  half8_t zh = {};
  half8_t A2 = (lane < 32) ? A1 : zh;  // [q1|0]
  const half8_t* kbase = (const half8_t*)(k2 + (size_t)bh * 2304 * 32);

  // this lane's rowblk in the logit cache (4-row group rowtile*4+quad)
  uint2* dstRow =
      STORE ? (lgG + ((size_t)bh * 576 + rowtile * 4 + quad) * 2304) : nullptr;

  // ---- pass 1: row max (+ store packed f16 logits) ----
  float mreg[4] = {NEG_INF, NEG_INF, NEG_INF, NEG_INF};
#pragma unroll 4
  for (int t = 0; t < 36; t++) {
    int col = wave * 576 + t * 16 + m16;
    const half8_t* kk = kbase + (size_t)col * 4;
    half8_t b1 = kk[quad & 1];        // k1 halves
    half8_t b2 = kk[2 + (quad & 1)];  // kr halves
    floatx4 acc = {};
    acc = __builtin_amdgcn_mfma_f32_16x16x32_f16(A2, b2, acc, 0, 0, 0);
    acc = __builtin_amdgcn_mfma_f32_16x16x32_f16(A1, b1, acc, 0, 0, 0);
#pragma unroll
    for (int i = 0; i < 4; i++) mreg[i] = fmaxf(mreg[i], acc[i]);
    if (STORE) {
      __half2 h01 = __floats2half2_rn(acc[0], acc[1]);
      __half2 h23 = __floats2half2_rn(acc[2], acc[3]);
      uint2 packed;
      packed.x = *(unsigned*)&h01;
      packed.y = *(unsigned*)&h23;
      dstRow[col] = packed;
    }
  }
#pragma unroll
  for (int off = 1; off < 16; off <<= 1)
#pragma unroll
    for (int i = 0; i < 4; i++)
      mreg[i] = fmaxf(mreg[i], __shfl_xor(mreg[i], off));

  __shared__ float mWv[4][16], sWv[4][16], uWv[4][16];
  if (m16 == 0) {
#pragma unroll
    for (int i = 0; i < 4; i++) mWv[wave][quad * 4 + i] = mreg[i];
  }
  __syncthreads();
  float mrow[4];
#pragma unroll
  for (int i = 0; i < 4; i++) {
    int r = quad * 4 + i;
    mrow[i] = fmaxf(fmaxf(mWv[0][r], mWv[1][r]), fmaxf(mWv[2][r], mWv[3][r]));
  }

  // ---- pass 2: S = sum e^z, U = sum z e^z (z = a - m) ----
  float s[4] = {0.f, 0.f, 0.f, 0.f}, u[4] = {0.f, 0.f, 0.f, 0.f};
#pragma unroll 4
  for (int t = 0; t < 36; t++) {
    int col = wave * 576 + t * 16 + m16;
    const half8_t* kk = kbase + (size_t)col * 4;
    half8_t b1 = kk[quad & 1];
    half8_t b2 = kk[2 + (quad & 1)];
    floatx4 acc = {};
    acc = __builtin_amdgcn_mfma_f32_16x16x32_f16(A2, b2, acc, 0, 0, 0);
    acc = __builtin_amdgcn_mfma_f32_16x16x32_f16(A1, b1, acc, 0, 0, 0);
#pragma unroll
    for (int i = 0; i < 4; i++) {
      float z = acc[i] - mrow[i];
      float e = __expf(z);
      s[i] += e;
      u[i] = fmaf(z, e, u[i]);
    }
  }
#pragma unroll
  for (int off = 1; off < 16; off <<= 1) {
#pragma unroll
    for (int i = 0; i < 4; i++) {
      s[i] += __shfl_xor(s[i], off);
      u[i] += __shfl_xor(u[i], off);
    }
  }
  if (m16 == 0) {
#pragma unroll
    for (int i = 0; i < 4; i++) {
      sWv[wave][quad * 4 + i] = s[i];
      uWv[wave][quad * 4 + i] = u[i];
    }
  }
  __syncthreads();
  if (tid < 16) {
    float S = sWv[0][tid] + sWv[1][tid] + sWv[2][tid] + sWv[3][tid];
    float U = uWv[0][tid] + uWv[1][tid] + uWv[2][tid] + uWv[3][tid];
    float er = __logf(S) - U / S;
    er += __shfl_xor(er, 1);
    er += __shfl_xor(er, 2);
    er += __shfl_xor(er, 4);
    er += __shfl_xor(er, 8);
    if (tid == 0) atomicAdd(&ent[bh], er);
  }
}

// K5: gate MLP + phase A (CACHED: 9 uint2 loads of f16 logits; else MFMA
// recompute) + per-row exact k-th (16-bit ballot) + masked softmax + PV.
template <bool CACHED>
__global__ __launch_bounds__(256, 7) void k_attn_t(
    const _Float16* __restrict__ q2, const _Float16* __restrict__ k2,
    const float* __restrict__ vh, const uint2* __restrict__ lgG,
    const float* __restrict__ ent, const float* __restrict__ Wg1,
    const float* __restrict__ bg1, const float* __restrict__ Wg2,
    const float* __restrict__ bg2, float* __restrict__ oh) {
  // 2304 j * 4 rows * 2B = 18432 B; also reused as fp32 reduce buf (16640 B).
  __shared__ __align__(16) unsigned long long ldsRaw[18432 / 8];
  __shared__ float mSh[4][4];
  __shared__ float thSh[4];
  __shared__ float sShW[4][4];

  uint2* lgt64 = (uint2*)ldsRaw;                              // [j] -> 4 halfs
  const unsigned short* lgtU = (const unsigned short*)ldsRaw; // [j*4+r]

  int blk = blockIdx.x;
  int rowblk = blk % 576;
  int bh = blk / 576;
  int row0 = rowblk * 4;
  int tid = threadIdx.x, lane = tid & 63, wave = tid >> 6;

  const float4* vb = (const float4*)(vh + (size_t)bh * 2304 * 16);

  // ---- gate MLP: keep count (uniform across block) ----
  float eAvg = ent[bh] * (1.f / 2304.f);
  float gacc = bg2[0];
#pragma unroll
  for (int i = 0; i < 16; i++) {
    float h = fmaxf(fmaf(eAvg, Wg1[i], bg1[i]), 0.f);
    gacc = fmaf(h, Wg2[i], gacc);
  }
  float ratio = 0.9f / (1.f + __expf(-gacc)) + 0.1f;
  int kp = (int)ceilf(ratio * 2304.f);
  unsigned keep = (unsigned)min(max(kp, 1), 2304);

  // ---- phase A: logits -> LDS (f16, [j][r]); row max ----
  float mloc[4] = {NEG_INF, NEG_INF, NEG_INF, NEG_INF};
  if (CACHED) {
    const uint2* src = lgG + (size_t)blk * 2304;
#pragma unroll
    for (int jj = 0; jj < 9; jj++) {
      int j = tid + jj * 256;
      uint2 raw = src[j];
      lgt64[j] = raw;
      float2 a01 = __half22float2(*(__half2*)&raw.x);
      float2 a23 = __half22float2(*(__half2*)&raw.y);
      mloc[0] = fmaxf(mloc[0], a01.x);
      mloc[1] = fmaxf(mloc[1], a01.y);
      mloc[2] = fmaxf(mloc[2], a23.x);
      mloc[3] = fmaxf(mloc[3], a23.y);
    }
  } else {
    int m16 = lane & 15, quad = lane >> 4;
    const half8_t* q2v =
        (const half8_t*)(q2 + ((size_t)bh * 2304 + row0 + (m16 & 3)) * 32);
    half8_t A1 = q2v[quad];
    half8_t zh = {};
    half8_t A2 = (lane < 32) ? A1 : zh;
    const half8_t* kbase = (const half8_t*)(k2 + (size_t)bh * 2304 * 32);
#pragma unroll 4
    for (int t = 0; t < 36; t++) {
      int ct = wave * 36 + t;
      int col = ct * 16 + m16;
      const half8_t* kk = kbase + (size_t)col * 4;
      half8_t b1 = kk[quad & 1];
      half8_t b2 = kk[2 + (quad & 1)];
      floatx4 acc = {};
      acc = __builtin_amdgcn_mfma_f32_16x16x32_f16(A2, b2, acc, 0, 0, 0);
      acc = __builtin_amdgcn_mfma_f32_16x16x32_f16(A1, b1, acc, 0, 0, 0);
      if (lane < 16) {
        int j = ct * 16 + lane;
        __half2 h01 = __floats2half2_rn(acc[0], acc[1]);
        __half2 h23 = __floats2half2_rn(acc[2], acc[3]);
        uint2 packed;
        packed.x = *(unsigned*)&h01;
        packed.y = *(unsigned*)&h23;
        lgt64[j] = packed;
#pragma unroll
        for (int i = 0; i < 4; i++) mloc[i] = fmaxf(mloc[i], acc[i]);
      }
    }
  }
#pragma unroll
  for (int off = 1; off < 64; off <<= 1)
#pragma unroll
    for (int r = 0; r < 4; r++)
      mloc[r] = fmaxf(mloc[r], __shfl_xor(mloc[r], off));
  if (lane == 0) {
#pragma unroll
    for (int r = 0; r < 4; r++) mSh[wave][r] = mloc[r];
  }
  __syncthreads();
  float m[4];
#pragma unroll
  for (int r = 0; r < 4; r++)
    m[r] = fmaxf(fmaxf(mSh[0][r], mSh[1][r]), fmaxf(mSh[2][r], mSh[3][r]));

  // ---- phase B: row-per-wave exact k-th largest on 16-bit keys ----
  {
    int r = wave;  // each wave owns one row
    unsigned keys[36];
#pragma unroll
    for (int i = 0; i < 36; i++) {
      int j = lane + i * 64;
      keys[i] = h2key(lgtU[j * 4 + r]);
    }
    unsigned T = 0u;
    for (int bit = 15; bit >= 0; --bit) {
      unsigned cand = T | (1u << bit);
      unsigned cnt = 0u;
#pragma unroll
      for (int i = 0; i < 36; i++)
        cnt += (unsigned)__popcll(__ballot(keys[i] >= cand));
      if (cnt >= keep) {
        T = cand;  // uniform
        if (cnt == keep) break;
      }
    }
    if (lane == 0) thSh[r] = key16_to_float(T);
  }
  __syncthreads();  // all phase-B LDS reads done; th visible
  float th[4];
#pragma unroll
  for (int r = 0; r < 4; r++) th[r] = thSh[r];

  // ---- phase C1: p = masked exp, in-place (f16); sp partials ----
  float sp[4] = {0.f, 0.f, 0.f, 0.f};
#pragma unroll
  for (int jj = 0; jj < 9; jj++) {
    int j = tid + jj * 256;
    uint2 raw = lgt64[j];
    __half2 h01 = *(__half2*)&raw.x;
    __half2 h23 = *(__half2*)&raw.y;
    float2 a01 = __half22float2(h01);
    float2 a23 = __half22float2(h23);
    float av[4] = {a01.x, a01.y, a23.x, a23.y};
    float p[4];
#pragma unroll
    for (int r = 0; r < 4; r++) {
      p[r] = (av[r] >= th[r]) ? __expf(av[r] - m[r]) : 0.f;
      sp[r] += p[r];
    }
    __half2 p01 = __floats2half2_rn(p[0], p[1]);
    __half2 p23 = __floats2half2_rn(p[2], p[3]);
    uint2 packed;
    packed.x = *(unsigned*)&p01;
    packed.y = *(unsigned*)&p23;
    lgt64[j] = packed;
  }
#pragma unroll
  for (int off = 1; off < 64; off <<= 1)
#pragma unroll
    for (int r = 0; r < 4; r++) sp[r] += __shfl_xor(sp[r], off);
  if (lane == 0) {
#pragma unroll
    for (int r = 0; r < 4; r++) sShW[wave][r] = sp[r];
  }
  __syncthreads();

  // ---- phase C2: dense PV from f16 probs, d-quad split ----
  int dg = tid & 3, jg = tid >> 2;
  float acc[4][4];
#pragma unroll
  for (int r = 0; r < 4; r++)
#pragma unroll
    for (int i = 0; i < 4; i++) acc[r][i] = 0.f;
  for (int jj = 0; jj < 36; jj++) {
    int j = jg + jj * 64;
    float4 v4 = vb[j * 4 + dg];
    uint2 raw = lgt64[j];
    float2 p01 = __half22float2(*(__half2*)&raw.x);
    float2 p23 = __half22float2(*(__half2*)&raw.y);
    float p[4] = {p01.x, p01.y, p23.x, p23.y};
#pragma unroll
    for (int r = 0; r < 4; r++) {
      acc[r][0] = fmaf(p[r], v4.x, acc[r][0]);
      acc[r][1] = fmaf(p[r], v4.y, acc[r][1]);
      acc[r][2] = fmaf(p[r], v4.z, acc[r][2]);
      acc[r][3] = fmaf(p[r], v4.w, acc[r][3]);
    }
  }

  // ---- phase D: reduce over 64 j-groups via padded LDS (fp32 view) ----
  __syncthreads();  // all prob reads done; reuse buffer
  float* part = (float*)ldsRaw;  // stride 65 floats per j-group (16640 B)
#pragma unroll
  for (int r = 0; r < 4; r++)
#pragma unroll
    for (int i = 0; i < 4; i++)
      part[jg * 65 + r * 16 + dg * 4 + i] = acc[r][i];
  __syncthreads();
  if (tid < 64) {
    float t2 = 0.f;
    for (int g = 0; g < 64; g++) t2 += part[g * 65 + tid];
    int r = tid >> 4, d = tid & 15;
    float S = sShW[0][r] + sShW[1][r] + sShW[2][r] + sShW[3][r];
    oh[((size_t)(bh * 2304 + row0 + r)) * 16 + d] = t2 / S;
  }
}

// K6: output projection out[b,co,pos] = Wproj @ heads + bproj
__global__ __launch_bounds__(256) void k_proj(const float* __restrict__ oh,
                                              const float* __restrict__ Wp,
                                              const float* __restrict__ bp,
                                              float* __restrict__ out) {
  int blk = blockIdx.x;
  int chunk = blk % 9;
  int co = (blk / 9) % 64;
  int b = blk / (9 * 64);
  int pos = chunk * 256 + threadIdx.x;
  const float* wr = Wp + co * 64;
  float acc = bp[co];
#pragma unroll
  for (int head = 0; head < 4; head++) {
    const float4* op = (const float4*)(oh + ((size_t)((b * 4 + head) * 2304 + pos)) * 16);
#pragma unroll
    for (int p = 0; p < 4; p++) {
      float4 o4 = op[p];
      acc = fmaf(wr[head * 16 + p * 4 + 0], o4.x, acc);
      acc = fmaf(wr[head * 16 + p * 4 + 1], o4.y, acc);
      acc = fmaf(wr[head * 16 + p * 4 + 2], o4.z, acc);
      acc = fmaf(wr[head * 16 + p * 4 + 3], o4.w, acc);
    }
  }
  out[(b * 64 + co) * 2304 + pos] = acc;
}

extern "C" void kernel_launch(void* const* d_in, const int* in_sizes, int n_in,
                              void* d_out, int out_size, void* d_ws,
                              size_t ws_size, hipStream_t stream) {
  const float* x    = (const float*)d_in[0];
  const float* Wqkv = (const float*)d_in[1];
  const float* bqkv = (const float*)d_in[2];
  const float* Wpos = (const float*)d_in[3];
  const float* bpos = (const float*)d_in[4];
  const float* Wg1  = (const float*)d_in[5];
  const float* bg1  = (const float*)d_in[6];
  const float* Wg2  = (const float*)d_in[7];
  const float* bg2  = (const float*)d_in[8];
  const float* Wpr  = (const float*)d_in[9];
  const float* bpr  = (const float*)d_in[10];
  float* out = (float*)d_out;

  // f16 logit cache: 8*576 rowblks * 2304 j * 8 B = 84,934,656 B
  const size_t lgBytes = (size_t)8 * 576 * 2304 * 8;
  const size_t baseBytes =
      (size_t)(884736 + 2 * 294912 + 8) * 4 + (size_t)2 * 589824 * 2;
  bool cached = ws_size >= lgBytes + baseBytes;

  char* base = (char*)d_ws;
  uint2* lgG = nullptr;
  if (cached) {
    lgG = (uint2*)base;
    base += lgBytes;
  }
  float* qkv_raw = (float*)base;      // 2*192*2304 = 884736 floats
  float* vh = qkv_raw + 884736;       // 294912 floats
  float* oh = vh + 294912;            // 294912 floats
  float* ent = oh + 294912;           // 8 floats
  _Float16* q2 = (_Float16*)(ent + 8);        // 8*2304*32 = 589824 halves
  _Float16* k2 = q2 + 589824;                 // 589824 halves

  (void)hipMemsetAsync(ent, 0, 8 * sizeof(float), stream);
  hipLaunchKernelGGL(k_qkv, dim3(2 * 192 * 9), dim3(256), 0, stream,
                     x, Wqkv, bqkv, qkv_raw);
  hipLaunchKernelGGL(k_dw, dim3(2 * 192 * 9), dim3(256), 0, stream,
                     qkv_raw, Wpos, bpos, q2, k2, vh);
  if (cached) {
    hipLaunchKernelGGL((k_ent_t<true>), dim3(8 * 144), dim3(256), 0, stream,
                       q2, k2, ent, lgG);
    hipLaunchKernelGGL((k_attn_t<true>), dim3(8 * 576), dim3(256), 0, stream,
                       q2, k2, vh, lgG, ent, Wg1, bg1, Wg2, bg2, oh);
  } else {
    hipLaunchKernelGGL((k_ent_t<false>), dim3(8 * 144), dim3(256), 0, stream,
                       q2, k2, ent, lgG);
    hipLaunchKernelGGL((k_attn_t<false>), dim3(8 * 576), dim3(256), 0, stream,
                       q2, k2, vh, lgG, ent, Wg1, bg1, Wg2, bg2, oh);
  }
  hipLaunchKernelGGL(k_proj, dim3(2 * 64 * 9), dim3(256), 0, stream,
                     oh, Wpr, bpr, out);
}

// Round 9
// 229.241 us; speedup vs baseline: 1.2680x; 1.0542x over previous
//
#include <hip/hip_runtime.h>
#include <hip/hip_fp16.h>

// b=2, c=64, 48x48 -> n=2304, heads=4, hd=16. n = 9*256 = 144*16.
// QK^T: q,k as f16 split pairs [v16|res16]; 2 MFMAs give fp32-ish logits
// (verified r7/r8). k_ent computes QK^T once, stores f16 logit cache
// ROW-MAJOR [bh][row][j] (LDS-transposed, 128B chunks). k_attn: phase A =
// coalesced row loads; phases A/B/C1 wave-private per row; PV via MFMA
// (p rows are A-fragments; V^T f16 [d][j] rows are B-fragments).

#define NEG_INF (-__builtin_huge_valf())

typedef _Float16 half8_t __attribute__((ext_vector_type(8)));
typedef float floatx4 __attribute__((ext_vector_type(4)));

__device__ __forceinline__ unsigned h2key(unsigned short u) {
  return (u & 0x8000u) ? (unsigned)((~u) & 0xFFFFu) : (unsigned)(u | 0x8000u);
}
__device__ __forceinline__ float key16_to_float(unsigned k) {
  unsigned short u = (k & 0x8000u) ? (unsigned short)(k & 0x7FFFu)
                                   : (unsigned short)((~k) & 0xFFFFu);
  return __half2float(__ushort_as_half(u));
}

__device__ __forceinline__ float max8(uint4 v, float mx) {
  float2 f0 = __half22float2(*(__half2*)&v.x);
  float2 f1 = __half22float2(*(__half2*)&v.y);
  float2 f2 = __half22float2(*(__half2*)&v.z);
  float2 f3 = __half22float2(*(__half2*)&v.w);
  mx = fmaxf(mx, fmaxf(fmaxf(f0.x, f0.y), fmaxf(f1.x, f1.y)));
  mx = fmaxf(mx, fmaxf(fmaxf(f2.x, f2.y), fmaxf(f3.x, f3.y)));
  return mx;
}

__device__ __forceinline__ uint4 maskExp8(uint4 v, float th, float m,
                                          float& sp) {
  float2 f0 = __half22float2(*(__half2*)&v.x);
  float2 f1 = __half22float2(*(__half2*)&v.y);
  float2 f2 = __half22float2(*(__half2*)&v.z);
  float2 f3 = __half22float2(*(__half2*)&v.w);
  float p0 = (f0.x >= th) ? __expf(f0.x - m) : 0.f;
  float p1 = (f0.y >= th) ? __expf(f0.y - m) : 0.f;
  float p2 = (f1.x >= th) ? __expf(f1.x - m) : 0.f;
  float p3 = (f1.y >= th) ? __expf(f1.y - m) : 0.f;
  float p4 = (f2.x >= th) ? __expf(f2.x - m) : 0.f;
  float p5 = (f2.y >= th) ? __expf(f2.y - m) : 0.f;
  float p6 = (f3.x >= th) ? __expf(f3.x - m) : 0.f;
  float p7 = (f3.y >= th) ? __expf(f3.y - m) : 0.f;
  sp += ((p0 + p1) + (p2 + p3)) + ((p4 + p5) + (p6 + p7));
  uint4 o;
  __half2 h0 = __floats2half2_rn(p0, p1); o.x = *(unsigned*)&h0;
  __half2 h1 = __floats2half2_rn(p2, p3); o.y = *(unsigned*)&h1;
  __half2 h2 = __floats2half2_rn(p4, p5); o.z = *(unsigned*)&h2;
  __half2 h3 = __floats2half2_rn(p6, p7); o.w = *(unsigned*)&h3;
  return o;
}

// K1: 1x1 conv qkv = Wqkv @ x + bqkv.
__global__ __launch_bounds__(256) void k_qkv(const float* __restrict__ x,
                                             const float* __restrict__ W,
                                             const float* __restrict__ bias,
                                             float* __restrict__ out) {
  int blk = blockIdx.x;
  int chunk = blk % 9;
  int o = (blk / 9) % 192;
  int b = blk / (9 * 192);
  int pos = chunk * 256 + threadIdx.x;
  const float* xb = x + b * 64 * 2304 + pos;
  const float* wr = W + o * 64;
  float acc = bias[o];
#pragma unroll
  for (int c = 0; c < 64; c++) acc = fmaf(wr[c], xb[c * 2304], acc);
  out[(b * 192 + o) * 2304 + pos] = acc;
}

// K2: 3x3 depthwise conv + bias. q/k -> f16 split pairs [row][v16|res16];
// v -> f16 V^T [bh][d][j] (coalesced 2B-contiguous stores).
__global__ __launch_bounds__(256) void k_dw(const float* __restrict__ qkv,
                                            const float* __restrict__ Wpos,
                                            const float* __restrict__ bpos,
                                            _Float16* __restrict__ q2,
                                            _Float16* __restrict__ k2,
                                            _Float16* __restrict__ vt) {
  int blk = blockIdx.x;
  int chunk = blk % 9;
  int ch = (blk / 9) % 192;
  int b = blk / (9 * 192);
  int pos = chunk * 256 + threadIdx.x;
  int yy = pos / 48, xx = pos % 48;
  const float* in = qkv + (b * 192 + ch) * 2304;
  const float* w = Wpos + ch * 9;
  float acc = bpos[ch];
#pragma unroll
  for (int dy = -1; dy <= 1; dy++) {
    int y2 = yy + dy;
    if ((unsigned)y2 < 48u) {
#pragma unroll
      for (int dx = -1; dx <= 1; dx++) {
        int x2 = xx + dx;
        if ((unsigned)x2 < 48u)
          acc = fmaf(w[(dy + 1) * 3 + (dx + 1)], in[y2 * 48 + x2], acc);
      }
    }
  }
  int sel = ch >> 6;
  int c = ch & 63;
  int head = c >> 4, d = c & 15;
  int bh = b * 4 + head;
  if (sel == 2) {
    vt[((size_t)bh * 16 + d) * 2304 + pos] = (_Float16)acc;
  } else {
    if (sel == 0) acc *= 0.25f;  // softmax scale folded into q
    size_t idx = (size_t)bh * 2304 + pos;
    _Float16 h1 = (_Float16)acc;
    float r = acc - (float)h1;
    _Float16 h2 = (_Float16)r;
    _Float16* dst = (sel == 0) ? q2 : k2;
    dst[idx * 32 + d] = h1;
    dst[idx * 32 + 16 + d] = h2;
  }
}

// K3: MFMA QK^T once: entropy + (STORE) row-major f16 logit cache.
// grid = 8 bh * 144 rowtiles (16 rows); wave w covers cols [w*576,..).
// Transpose via LDS: 16x64-col staging per wave, flushed as 128B row-chunks.
template <bool STORE>
__global__ __launch_bounds__(256) void k_ent_t(const _Float16* __restrict__ q2,
                                               const _Float16* __restrict__ k2,
                                               float* __restrict__ ent,
                                               _Float16* __restrict__ lgH) {
  __shared__ __align__(16) _Float16 tBuf[4][16][72];  // [wave][row16][64+8 pad]
  __shared__ float mWv[4][16], sWv[4][16], uWv[4][16];

  int blk = blockIdx.x;
  int rowtile = blk % 144;
  int bh = blk / 144;
  int row0 = rowtile * 16;
  int tid = threadIdx.x, lane = tid & 63, wave = tid >> 6;
  int m16 = lane & 15, quad = lane >> 4;

  const half8_t* q2v =
      (const half8_t*)(q2 + ((size_t)bh * 2304 + row0 + m16) * 32);
  half8_t A1 = q2v[quad];
  half8_t zh = {};
  half8_t A2 = (lane < 32) ? A1 : zh;
  const half8_t* kbase = (const half8_t*)(k2 + (size_t)bh * 2304 * 32);

  // ---- pass 1: row max (+ transposed cache store) ----
  float mreg[4] = {NEG_INF, NEG_INF, NEG_INF, NEG_INF};
  for (int g = 0; g < 9; g++) {
#pragma unroll
    for (int tt = 0; tt < 4; tt++) {
      int t = g * 4 + tt;
      int col = wave * 576 + t * 16 + m16;
      const half8_t* kk = kbase + (size_t)col * 4;
      half8_t b1 = kk[quad & 1];
      half8_t b2 = kk[2 + (quad & 1)];
      floatx4 acc = {};
      acc = __builtin_amdgcn_mfma_f32_16x16x32_f16(A2, b2, acc, 0, 0, 0);
      acc = __builtin_amdgcn_mfma_f32_16x16x32_f16(A1, b1, acc, 0, 0, 0);
#pragma unroll
      for (int i = 0; i < 4; i++) {
        mreg[i] = fmaxf(mreg[i], acc[i]);
        if (STORE) tBuf[wave][quad * 4 + i][tt * 16 + m16] = (_Float16)acc[i];
      }
    }
    if (STORE) {
      __syncthreads();  // drain LDS writes (cross-lane within wave)
      int rb = lane >> 3, seg = lane & 7;
#pragma unroll
      for (int it = 0; it < 2; it++) {
        int rr = it * 8 + rb;
        uint4 vv = *(const uint4*)&tBuf[wave][rr][seg * 8];
        *(uint4*)(lgH + ((size_t)bh * 2304 + row0 + rr) * 2304 + wave * 576 +
                  g * 64 + seg * 8) = vv;
      }
      __syncthreads();
    }
  }
#pragma unroll
  for (int off = 1; off < 16; off <<= 1)
#pragma unroll
    for (int i = 0; i < 4; i++)
      mreg[i] = fmaxf(mreg[i], __shfl_xor(mreg[i], off));
  if (m16 == 0) {
#pragma unroll
    for (int i = 0; i < 4; i++) mWv[wave][quad * 4 + i] = mreg[i];
  }
  __syncthreads();
  float mrow[4];
#pragma unroll
  for (int i = 0; i < 4; i++) {
    int r = quad * 4 + i;
    mrow[i] = fmaxf(fmaxf(mWv[0][r], mWv[1][r]), fmaxf(mWv[2][r], mWv[3][r]));
  }

  // ---- pass 2: S = sum e^z, U = sum z e^z ----
  float s[4] = {0.f, 0.f, 0.f, 0.f}, u[4] = {0.f, 0.f, 0.f, 0.f};
#pragma unroll 4
  for (int t = 0; t < 36; t++) {
    int col = wave * 576 + t * 16 + m16;
    const half8_t* kk = kbase + (size_t)col * 4;
    half8_t b1 = kk[quad & 1];
    half8_t b2 = kk[2 + (quad & 1)];
    floatx4 acc = {};
    acc = __builtin_amdgcn_mfma_f32_16x16x32_f16(A2, b2, acc, 0, 0, 0);
    acc = __builtin_amdgcn_mfma_f32_16x16x32_f16(A1, b1, acc, 0, 0, 0);
#pragma unroll
    for (int i = 0; i < 4; i++) {
      float z = acc[i] - mrow[i];
      float e = __expf(z);
      s[i] += e;
      u[i] = fmaf(z, e, u[i]);
    }
  }
#pragma unroll
  for (int off = 1; off < 16; off <<= 1) {
#pragma unroll
    for (int i = 0; i < 4; i++) {
      s[i] += __shfl_xor(s[i], off);
      u[i] += __shfl_xor(u[i], off);
    }
  }
  if (m16 == 0) {
#pragma unroll
    for (int i = 0; i < 4; i++) {
      sWv[wave][quad * 4 + i] = s[i];
      uWv[wave][quad * 4 + i] = u[i];
    }
  }
  __syncthreads();
  if (tid < 16) {
    float S = sWv[0][tid] + sWv[1][tid] + sWv[2][tid] + sWv[3][tid];
    float U = uWv[0][tid] + uWv[1][tid] + uWv[2][tid] + uWv[3][tid];
    float er = __logf(S) - U / S;
    er += __shfl_xor(er, 1);
    er += __shfl_xor(er, 2);
    er += __shfl_xor(er, 4);
    er += __shfl_xor(er, 8);
    if (tid == 0) atomicAdd(&ent[bh], er);
  }
}

// K5: gate MLP + per-row top-k + masked softmax + MFMA PV.
// LDS p: row-major f16 [4][2320]. Wave r owns row r through A/B/C1 (no
// barriers); C2: each wave a j-quarter of the PV matmul via MFMA.
template <bool CACHED>
__global__ __launch_bounds__(256, 7) void k_attn_t(
    const _Float16* __restrict__ q2, const _Float16* __restrict__ k2,
    const _Float16* __restrict__ vt, const _Float16* __restrict__ lgH,
    const float* __restrict__ ent, const float* __restrict__ Wg1,
    const float* __restrict__ bg1, const float* __restrict__ Wg2,
    const float* __restrict__ bg2, float* __restrict__ oh) {
  __shared__ __align__(16) _Float16 pbuf[4][2320];
  __shared__ float sS[4];
  __shared__ float mShF[4][4];  // fallback only
  __shared__ __align__(16) float redSh[4][64];

  int blk = blockIdx.x;
  int rowblk = blk % 576;
  int bh = blk / 576;
  int row0 = rowblk * 4;
  int tid = threadIdx.x, lane = tid & 63, wave = tid >> 6;

  // ---- gate MLP (uniform) ----
  float eAvg = ent[bh] * (1.f / 2304.f);
  float gacc = bg2[0];
#pragma unroll
  for (int i = 0; i < 16; i++) {
    float h = fmaxf(fmaf(eAvg, Wg1[i], bg1[i]), 0.f);
    gacc = fmaf(h, Wg2[i], gacc);
  }
  float ratio = 0.9f / (1.f + __expf(-gacc)) + 0.1f;
  int kp = (int)ceilf(ratio * 2304.f);
  unsigned keep = (unsigned)min(max(kp, 1), 2304);

  // ---- phase A: own row -> LDS; own-row max ----
  float m;
  uint4* dst4 = (uint4*)pbuf[wave];
  if (CACHED) {
    const uint4* src =
        (const uint4*)(lgH + ((size_t)bh * 2304 + row0 + wave) * 2304);
    float mx = NEG_INF;
#pragma unroll
    for (int it = 0; it < 4; it++) {
      int idx = lane + it * 64;
      uint4 v = src[idx];
      dst4[idx] = v;
      mx = max8(v, mx);
    }
    if (lane < 32) {
      uint4 v = src[256 + lane];
      dst4[256 + lane] = v;
      mx = max8(v, mx);
    }
#pragma unroll
    for (int off = 1; off < 64; off <<= 1) mx = fmaxf(mx, __shfl_xor(mx, off));
    m = mx;
  } else {
    int m16 = lane & 15, quad = lane >> 4;
    const half8_t* q2v =
        (const half8_t*)(q2 + ((size_t)bh * 2304 + row0 + (m16 & 3)) * 32);
    half8_t A1 = q2v[quad];
    half8_t zh = {};
    half8_t A2 = (lane < 32) ? A1 : zh;
    const half8_t* kbase = (const half8_t*)(k2 + (size_t)bh * 2304 * 32);
    float ml[4] = {NEG_INF, NEG_INF, NEG_INF, NEG_INF};
#pragma unroll 4
    for (int t = 0; t < 36; t++) {
      int ct = wave * 36 + t;
      int col = ct * 16 + m16;
      const half8_t* kk = kbase + (size_t)col * 4;
      half8_t b1 = kk[quad & 1];
      half8_t b2 = kk[2 + (quad & 1)];
      floatx4 acc = {};
      acc = __builtin_amdgcn_mfma_f32_16x16x32_f16(A2, b2, acc, 0, 0, 0);
      acc = __builtin_amdgcn_mfma_f32_16x16x32_f16(A1, b1, acc, 0, 0, 0);
      if (lane < 16) {
#pragma unroll
        for (int i = 0; i < 4; i++) {
          pbuf[i][ct * 16 + lane] = (_Float16)acc[i];
          ml[i] = fmaxf(ml[i], acc[i]);
        }
      }
    }
#pragma unroll
    for (int off = 1; off < 16; off <<= 1)
#pragma unroll
      for (int i = 0; i < 4; i++) ml[i] = fmaxf(ml[i], __shfl_xor(ml[i], off));
    if (lane == 0) {
#pragma unroll
      for (int i = 0; i < 4; i++) mShF[wave][i] = ml[i];
    }
    __syncthreads();
    m = fmaxf(fmaxf(mShF[0][wave], mShF[1][wave]),
              fmaxf(mShF[2][wave], mShF[3][wave]));
  }

  // ---- phase B: own-row exact k-th largest (16-bit ballot search) ----
  float th;
  {
    const unsigned short* prow = (const unsigned short*)pbuf[wave];
    unsigned keys[36];
#pragma unroll
    for (int i = 0; i < 36; i++) keys[i] = h2key(prow[lane + i * 64]);
    unsigned T = 0u;
    for (int bit = 15; bit >= 0; --bit) {
      unsigned cand = T | (1u << bit);
      unsigned cnt = 0u;
#pragma unroll
      for (int i = 0; i < 36; i++)
        cnt += (unsigned)__popcll(__ballot(keys[i] >= cand));
      if (cnt >= keep) {
        T = cand;  // uniform
        if (cnt == keep) break;
      }
    }
    th = key16_to_float(T);
  }

  // ---- phase C1: own-row masked exp in-place; S ----
  {
    float sp = 0.f;
#pragma unroll
    for (int it = 0; it < 4; it++) {
      int idx = lane + it * 64;
      dst4[idx] = maskExp8(dst4[idx], th, m, sp);
    }
    if (lane < 32) {
      int idx = 256 + lane;
      dst4[idx] = maskExp8(dst4[idx], th, m, sp);
    }
#pragma unroll
    for (int off = 1; off < 64; off <<= 1) sp += __shfl_xor(sp, off);
    if (lane == 0) sS[wave] = sp;
  }
  __syncthreads();  // all rows' p visible; sS visible

  // ---- phase C2: PV via MFMA; wave = j-quarter ----
  {
    int m16 = lane & 15, quad = lane >> 4;
    const _Float16* vrow = vt + ((size_t)bh * 16 + m16) * 2304;
    const _Float16* prow = pbuf[m16 & 3];
    int jb0 = wave * 576 + quad * 8;
    floatx4 acc = {};
#pragma unroll 6
    for (int t = 0; t < 18; t++) {
      int jb = jb0 + t * 32;
      half8_t a = *(const half8_t*)&prow[jb];
      half8_t b = *(const half8_t*)&vrow[jb];
      acc = __builtin_amdgcn_mfma_f32_16x16x32_f16(a, b, acc, 0, 0, 0);
    }
    if (lane < 16) {  // quad 0: D rows 0-3 = our rows, col = m16 = d
      *(floatx4*)&redSh[wave][m16 * 4] = acc;
    }
  }
  __syncthreads();
  if (tid < 64) {
    int r = tid & 3, d = tid >> 2;
    float s2 = redSh[0][d * 4 + r] + redSh[1][d * 4 + r] +
               redSh[2][d * 4 + r] + redSh[3][d * 4 + r];
    oh[((size_t)(bh * 2304 + row0 + r)) * 16 + d] = s2 / sS[r];
  }
}

// K6: output projection out[b,co,pos] = Wproj @ heads + bproj
__global__ __launch_bounds__(256) void k_proj(const float* __restrict__ oh,
                                              const float* __restrict__ Wp,
                                              const float* __restrict__ bp,
                                              float* __restrict__ out) {
  int blk = blockIdx.x;
  int chunk = blk % 9;
  int co = (blk / 9) % 64;
  int b = blk / (9 * 64);
  int pos = chunk * 256 + threadIdx.x;
  const float* wr = Wp + co * 64;
  float acc = bp[co];
#pragma unroll
  for (int head = 0; head < 4; head++) {
    const float4* op =
        (const float4*)(oh + ((size_t)((b * 4 + head) * 2304 + pos)) * 16);
#pragma unroll
    for (int p = 0; p < 4; p++) {
      float4 o4 = op[p];
      acc = fmaf(wr[head * 16 + p * 4 + 0], o4.x, acc);
      acc = fmaf(wr[head * 16 + p * 4 + 1], o4.y, acc);
      acc = fmaf(wr[head * 16 + p * 4 + 2], o4.z, acc);
      acc = fmaf(wr[head * 16 + p * 4 + 3], o4.w, acc);
    }
  }
  out[(b * 64 + co) * 2304 + pos] = acc;
}

extern "C" void kernel_launch(void* const* d_in, const int* in_sizes, int n_in,
                              void* d_out, int out_size, void* d_ws,
                              size_t ws_size, hipStream_t stream) {
  const float* x    = (const float*)d_in[0];
  const float* Wqkv = (const float*)d_in[1];
  const float* bqkv = (const float*)d_in[2];
  const float* Wpos = (const float*)d_in[3];
  const float* bpos = (const float*)d_in[4];
  const float* Wg1  = (const float*)d_in[5];
  const float* bg1  = (const float*)d_in[6];
  const float* Wg2  = (const float*)d_in[7];
  const float* bg2  = (const float*)d_in[8];
  const float* Wpr  = (const float*)d_in[9];
  const float* bpr  = (const float*)d_in[10];
  float* out = (float*)d_out;

  // row-major f16 logit cache: 8 bh * 2304 * 2304 * 2 B = 84,934,656 B
  const size_t lgBytes = (size_t)8 * 2304 * 2304 * 2;
  const size_t baseBytes = (size_t)(884736 + 294912 + 8) * 4 +
                           (size_t)(2 * 589824 + 294912) * 2;
  bool cached = ws_size >= lgBytes + baseBytes;

  char* base = (char*)d_ws;
  _Float16* lgH = nullptr;
  if (cached) {
    lgH = (_Float16*)base;
    base += lgBytes;
  }
  float* qkv_raw = (float*)base;        // 884736 floats
  float* oh = qkv_raw + 884736;         // 294912 floats
  float* ent = oh + 294912;             // 8 floats
  _Float16* q2 = (_Float16*)(ent + 8);  // 589824 halves
  _Float16* k2 = q2 + 589824;           // 589824 halves
  _Float16* vt = k2 + 589824;           // 294912 halves (V^T f16 [bh][d][j])

  (void)hipMemsetAsync(ent, 0, 8 * sizeof(float), stream);
  hipLaunchKernelGGL(k_qkv, dim3(2 * 192 * 9), dim3(256), 0, stream,
                     x, Wqkv, bqkv, qkv_raw);
  hipLaunchKernelGGL(k_dw, dim3(2 * 192 * 9), dim3(256), 0, stream,
                     qkv_raw, Wpos, bpos, q2, k2, vt);
  if (cached) {
    hipLaunchKernelGGL((k_ent_t<true>), dim3(8 * 144), dim3(256), 0, stream,
                       q2, k2, ent, lgH);
    hipLaunchKernelGGL((k_attn_t<true>), dim3(8 * 576), dim3(256), 0, stream,
                       q2, k2, vt, lgH, ent, Wg1, bg1, Wg2, bg2, oh);
  } else {
    hipLaunchKernelGGL((k_ent_t<false>), dim3(8 * 144), dim3(256), 0, stream,
                       q2, k2, ent, lgH);
    hipLaunchKernelGGL((k_attn_t<false>), dim3(8 * 576), dim3(256), 0, stream,
                       q2, k2, vt, lgH, ent, Wg1, bg1, Wg2, bg2, oh);
  }
  hipLaunchKernelGGL(k_proj, dim3(2 * 64 * 9), dim3(256), 0, stream,
                     oh, Wpr, bpr, out);
}